// Round 6
// baseline (8271.603 us; speedup 1.0000x reference)
//
#include <hip/hip_runtime.h>

// 2-layer LSTM (H1=128, H2=64, T=128, D_IN=2, B=2048) + FC(8192->11), fp32.
// R6: weights live in AGPRs (v_accvgpr_write/read inline asm, "a" constraints) —
// the VGPR allocator refused budgets >64 for 5 rounds (attributes ignored) and
// spilled 6+ GB/dispatch to scratch. Arch-VGPR live set now fits 64 by design:
// 4 batches/block, 512 blocks, acc[4][4]; xor-indexed batch accumulators reduced
// via DPP quad-perm + ds_swizzle. All LDS layouts hand-verified <=2-way banks.

#define TSTEPS 128
#define NCLS 11

// ws float-index layout:
//   wsA  [1024][64]  per-thread L1 weights            @ 0
//   wsB  [1024][48]  per-thread L2 weights            @ 65536
//   wsC  [8192][12]  Wfc transposed (+1 pad col)      @ 114688
//   h1s  [128][2048][128] layer-1 hidden states       @ 212992
#define WSA_OFF 0
#define WSB_OFF 65536
#define WSC_OFF 114688
#define H1S_OFF 212992

__device__ __forceinline__ float sigm(float x) { return 1.0f / (1.0f + __expf(-x)); }
__device__ __forceinline__ float tanh_(float x) { return 1.0f - 2.0f / (__expf(2.0f * x) + 1.0f); }

// AGPR stash/read. Writes define AGPR-resident SSA values; reads are volatile so
// they stay in-loop (no LICM into long-lived VGPRs -> no spill).
#define AW(agpr, v) asm volatile("v_accvgpr_write_b32 %0, %1" : "=a"(agpr) : "v"(v))
#define AR(v, agpr) asm volatile("v_accvgpr_read_b32 %0, %1" : "=v"(v) : "a"(agpr))

template<int C> __device__ __forceinline__ float dppmov(float v) {
    union { float f; int i; } u, r; u.f = v;
    r.i = __builtin_amdgcn_update_dpp(0, u.i, C, 0xf, 0xf, true);
    return r.f;
}
template<int P> __device__ __forceinline__ float swzl(float v) {
    union { float f; int i; } u, r; u.f = v;
    r.i = __builtin_amdgcn_ds_swizzle(u.i, P);
    return r.f;
}
// acc[j] at lane ks holds batch b=j^q (q=ks&3). Returns batch-q total over the
// ks&3 quad. 0xB1 = quad_perm xor1, 0x4E = quad_perm xor2.
__device__ __forceinline__ float xred4(float a0, float a1, float a2, float a3) {
    a0 += dppmov<0xB1>(a1);
    a2 += dppmov<0xB1>(a3);
    a0 += dppmov<0x4E>(a2);
    return a0;
}

// ---------------- prep: repack weights into per-thread layouts ----------------
__global__ void prep(const float* __restrict__ Whh1, const float* __restrict__ Wih2,
                     const float* __restrict__ Whh2, const float* __restrict__ Wfc,
                     float* __restrict__ ws) {
    int o = blockIdx.x * blockDim.x + threadIdx.x;
    if (o < 65536) {
        // wsA[tid][i]: tid=(d<<3)|ks, i=(g<<4)|j  -> Whh1[g*128+d][ks*16+j]
        int i = o & 63, tt = o >> 6;
        int ks = tt & 7, d = tt >> 3;
        int j = i & 15, g = i >> 4;
        ws[WSA_OFF + o] = Whh1[(g * 128 + d) * 128 + ks * 16 + j];
    } else if (o < 114688) {
        // wsB[tid][i]: tid=(d2<<4)|ks; i<32: Wih2 g=i>>3,k=ks*8+(i&7);
        //              i>=32: Whh2 g=(i-32)>>2, k=ks*4+(i&3)
        int p = o - 65536;
        int tt = p / 48, i = p % 48;
        int ks = tt & 15, d2 = tt >> 4;
        float v;
        if (i < 32) { int g = i >> 3, j = i & 7; v = Wih2[(g * 64 + d2) * 128 + ks * 8 + j]; }
        else { int i2 = i - 32; int g = i2 >> 2, j = i2 & 3; v = Whh2[(g * 64 + d2) * 64 + ks * 4 + j]; }
        ws[WSB_OFF + p] = v;
    } else if (o < 212992) {
        int p = o - 114688;
        int r = p / 12, c = p % 12;
        ws[WSC_OFF + p] = (c < NCLS) ? Wfc[c * 8192 + r] : 0.0f;
    }
}

// ---------------- kernel A: layer-1 LSTM, weights in AGPRs ----------------
// grid 512 x 1024 (2 block-rounds/CU). thread = (d = tid>>3, ks = tid&7).
// 4 batches/block; acc[j][g] = batch j^q over k-slice [ks*16, ks*16+16).
__global__ __launch_bounds__(1024) void lstm_l1(
    const float* __restrict__ x, const float* __restrict__ Wih1,
    float* __restrict__ ws) {
    __shared__ __align__(16) float lx[4 * 257];    // [b][c*128+t]
    __shared__ __align__(16) float lh1[4 * 132];   // [b][128+4pad]
    __shared__ __align__(16) float lwih[128 * 8];  // [d][g*2+c] input-proj coefs

    const int tid = threadIdx.x;
    const int ks = tid & 7, d = tid >> 3, q = ks & 3;
    const int b0 = blockIdx.x * 4;

    // 64 persistent weights -> AGPRs: wa[(g*4+jc)*4+c] = W[g][ks*16+jc*4+c]
    float wa[64];
    {
        const float4* wsrc = (const float4*)(ws + WSA_OFF) + tid * 16;
#pragma unroll
        for (int i = 0; i < 16; ++i) {
            float4 w4 = wsrc[i];
            AW(wa[4 * i + 0], w4.x); AW(wa[4 * i + 1], w4.y);
            AW(wa[4 * i + 2], w4.z); AW(wa[4 * i + 3], w4.w);
        }
    }

    // stage x (4 batches x 256) and Wih1 slice into LDS
    lx[(tid >> 8) * 257 + (tid & 255)] = x[b0 * 256 + tid];
    {   // lwih[dd*8 + g*2 + c] = Wih1[(g*128+dd)*2 + c]
        int dd = tid >> 3, g = (tid >> 1) & 3, c = tid & 1;
        lwih[tid] = Wih1[(g * 128 + dd) * 2 + c];
    }
    if (tid < 528) lh1[tid] = 0.0f;

    int off[4];
#pragma unroll
    for (int j = 0; j < 4; ++j) off[j] = ((j ^ q) * 132 + ks * 16) * 4;
    const char* lh1b = (const char*)lh1;
    const int lxb = q * 257;
    const float* wih = &lwih[d * 8];

    float* __restrict__ h1s = ws + H1S_OFF;
    const int sread = (tid >> 7) * 132 + (tid & 127);
    float c1 = 0.0f;
    __syncthreads();

    for (int t = 0; t < TSTEPS; ++t) {
        float acc[4][4];
#pragma unroll
        for (int j = 0; j < 4; ++j)
#pragma unroll
            for (int g = 0; g < 4; ++g) acc[j][g] = 0.0f;

#pragma unroll
        for (int jc = 0; jc < 4; ++jc) {
            float w[16];
#pragma unroll
            for (int g = 0; g < 4; ++g)
#pragma unroll
                for (int c = 0; c < 4; ++c) AR(w[g * 4 + c], wa[(g * 4 + jc) * 4 + c]);
#pragma unroll
            for (int j = 0; j < 4; ++j) {
                const float4 h = *(const float4*)(lh1b + off[j] + jc * 16);
#pragma unroll
                for (int g = 0; g < 4; ++g)
                    acc[j][g] += h.x * w[g * 4] + h.y * w[g * 4 + 1] +
                                 h.z * w[g * 4 + 2] + h.w * w[g * 4 + 3];
            }
        }
        float gi = xred4(acc[0][0], acc[1][0], acc[2][0], acc[3][0]);
        float gf = xred4(acc[0][1], acc[1][1], acc[2][1], acc[3][1]);
        float gg = xred4(acc[0][2], acc[1][2], acc[2][2], acc[3][2]);
        float go = xred4(acc[0][3], acc[1][3], acc[2][3], acc[3][3]);
        gi += swzl<0x101F>(gi);   // fold ks-bit2 (k halves)
        gf += swzl<0x101F>(gf);
        gg += swzl<0x101F>(gg);
        go += swzl<0x101F>(go);

        const float x0 = lx[lxb + t], x1 = lx[lxb + 128 + t];
        gi += wih[0] * x0 + wih[1] * x1;
        gf += wih[2] * x0 + wih[3] * x1;
        gg += wih[4] * x0 + wih[5] * x1;
        go += wih[6] * x0 + wih[7] * x1;

        const float i1 = sigm(gi), f1 = sigm(gf), g1 = tanh_(gg), o1 = sigm(go);
        c1 = f1 * c1 + i1 * g1;            // lane owns batch q (dup on ks,ks+4)
        const float h1n = o1 * tanh_(c1);

        __syncthreads();                   // all reads of old lh1 done
        if (ks < 4) lh1[ks * 132 + d] = h1n;
        __syncthreads();                   // new lh1 visible
        if (tid < 512) h1s[t * 262144 + b0 * 128 + tid] = lh1[sread];
    }
}

// ---------------- kernel B: layer-2 LSTM + fused FC, weights in AGPRs ----------------
// grid 512 x 1024. thread = (d2 = tid>>4, ks = tid&15); 4 batches/block.
// k-slice 12: h1 k in [ks*8,+8), h2 k in [ks*4,+4). b = j^q.
// lh1t: 2 replicas (ks>>3) at stride 560 words — bank shift 16, <=2-way verified.
__global__ __launch_bounds__(1024) void lstm_l2(
    const float* __restrict__ bfc, float* __restrict__ ws, float* __restrict__ out) {
    __shared__ __align__(16) float lh1t[2 * 1120]; // dbuf x (2 replicas x 560)
    __shared__ __align__(16) float lh2[4 * 72];    // stride 72: banks verified
    __shared__ __align__(16) float gfc[16 * 44];

    const int tid = threadIdx.x;
    const int ks = tid & 15, q = ks & 3, d2 = tid >> 4;
    const int b0 = blockIdx.x * 4;
    const float* __restrict__ h1s = ws + H1S_OFF;
    const float* __restrict__ wsc = ws + WSC_OFF;

    // 48 persistent weights -> AGPRs
    float wb[48];
    {
        const float4* wsrc = (const float4*)(ws + WSB_OFF) + tid * 12;
#pragma unroll
        for (int i = 0; i < 12; ++i) {
            float4 w4 = wsrc[i];
            AW(wb[4 * i + 0], w4.x); AW(wb[4 * i + 1], w4.y);
            AW(wb[4 * i + 2], w4.z); AW(wb[4 * i + 3], w4.w);
        }
    }

    if (tid < 288) lh2[tid] = 0.0f;

    int off1[4];
#pragma unroll
    for (int j = 0; j < 4; ++j)
        off1[j] = ((j ^ q) * 132 + ks * 8 + (ks >> 3) * 560) * 4;
    const char* lh1tb = (const char*)lh1t;
    const char* lh2b = (const char*)lh2;

    // staging lanes: tid<128: bs = tid>>5 (batch), k4 = tid&31 (float4 col)
    const int bs = tid >> 5, k4 = tid & 31;
    if (tid < 128) {
        float4 v = *(const float4*)(h1s + (b0 + bs) * 128 + k4 * 4);
        *(float4*)((char*)lh1t + (bs * 132 + k4 * 4) * 4) = v;
        *(float4*)((char*)lh1t + (bs * 132 + k4 * 4 + 560) * 4) = v;
    }

    float c2 = 0.0f;
    float facc[NCLS];
#pragma unroll
    for (int c = 0; c < NCLS; ++c) facc[c] = 0.0f;
    __syncthreads();

    for (int t = 0; t < TSTEPS; ++t) {
        const int bufoff = (t & 1) * 4480, nbufoff = 4480 - bufoff;
        float4 stg;
        const bool do_stage = (t < TSTEPS - 1) && (tid < 128);
        if (do_stage)
            stg = *(const float4*)(h1s + ((t + 1) * 2048 + b0 + bs) * 128 + k4 * 4);

        float acc[4][4];
#pragma unroll
        for (int j = 0; j < 4; ++j)
#pragma unroll
            for (int g = 0; g < 4; ++g) acc[j][g] = 0.0f;

#pragma unroll
        for (int jc = 0; jc < 2; ++jc) {   // h1 part: slice 8
            float w[16];
#pragma unroll
            for (int g = 0; g < 4; ++g)
#pragma unroll
                for (int c = 0; c < 4; ++c) AR(w[g * 4 + c], wb[g * 8 + jc * 4 + c]);
#pragma unroll
            for (int j = 0; j < 4; ++j) {
                const float4 h = *(const float4*)(lh1tb + bufoff + off1[j] + jc * 16);
#pragma unroll
                for (int g = 0; g < 4; ++g)
                    acc[j][g] += h.x * w[g * 4] + h.y * w[g * 4 + 1] +
                                 h.z * w[g * 4 + 2] + h.w * w[g * 4 + 3];
            }
        }
        {   // h2 part: slice 4
            float w[16];
#pragma unroll
            for (int g = 0; g < 4; ++g)
#pragma unroll
                for (int c = 0; c < 4; ++c) AR(w[g * 4 + c], wb[32 + g * 4 + c]);
#pragma unroll
            for (int j = 0; j < 4; ++j) {
                const int o2 = (((j ^ q) * 72 + ks * 4) << 2);
                const float4 h = *(const float4*)(lh2b + o2);
#pragma unroll
                for (int g = 0; g < 4; ++g)
                    acc[j][g] += h.x * w[g * 4] + h.y * w[g * 4 + 1] +
                                 h.z * w[g * 4 + 2] + h.w * w[g * 4 + 3];
            }
        }
        float gi = xred4(acc[0][0], acc[1][0], acc[2][0], acc[3][0]);
        float gf = xred4(acc[0][1], acc[1][1], acc[2][1], acc[3][1]);
        float gg = xred4(acc[0][2], acc[1][2], acc[2][2], acc[3][2]);
        float go = xred4(acc[0][3], acc[1][3], acc[2][3], acc[3][3]);
        gi += swzl<0x101F>(gi); gi += swzl<0x201F>(gi);   // fold ks bits 2,3
        gf += swzl<0x101F>(gf); gf += swzl<0x201F>(gf);
        gg += swzl<0x101F>(gg); gg += swzl<0x201F>(gg);
        go += swzl<0x101F>(go); go += swzl<0x201F>(go);

        const float i2 = sigm(gi), f2 = sigm(gf), g2 = tanh_(gg), o2v = sigm(go);
        c2 = f2 * c2 + i2 * g2;
        const float h2n = o2v * tanh_(c2);

        // fused FC: all lanes accumulate (b=q, d2); duplicates discarded at fold
        {
            const float4* wq = (const float4*)(wsc + (t * 64 + d2) * 12);
            const float4 q0 = wq[0], q1 = wq[1], q2 = wq[2];
            facc[0] += h2n * q0.x; facc[1] += h2n * q0.y; facc[2] += h2n * q0.z; facc[3] += h2n * q0.w;
            facc[4] += h2n * q1.x; facc[5] += h2n * q1.y; facc[6] += h2n * q1.z; facc[7] += h2n * q1.w;
            facc[8] += h2n * q2.x; facc[9] += h2n * q2.y; facc[10] += h2n * q2.z;
        }
        __syncthreads();                   // reads of lh1t[buf], lh2 done
        if (do_stage) {
            *(float4*)((char*)lh1t + nbufoff + (bs * 132 + k4 * 4) * 4) = stg;
            *(float4*)((char*)lh1t + nbufoff + (bs * 132 + k4 * 4 + 560) * 4) = stg;
        }
        if (ks < 4) lh2[q * 72 + d2] = h2n;
        __syncthreads();                   // staged tile + new lh2 visible
    }

    // FC fold: sum over the wave's 4 d2 values (lane bits 4,5)
#pragma unroll
    for (int c = 0; c < NCLS; ++c) {
        float v = facc[c];
        v += __shfl_xor(v, 16);
        v += __shfl_xor(v, 32);
        facc[c] = v;
    }
    const int w = tid >> 6;
    if ((tid & 63) < 4) {                  // lanes ks 0..3, d2-subgroup 0
#pragma unroll
        for (int c = 0; c < NCLS; ++c) gfc[w * 44 + (tid & 3) * 11 + c] = facc[c];
    }
    __syncthreads();
    if (tid < 44) {
        const int b = tid / 11, c = tid % 11;
        float s = bfc[c];
#pragma unroll
        for (int w2 = 0; w2 < 16; ++w2) s += gfc[w2 * 44 + tid];
        out[(b0 + b) * 11 + c] = s;
    }
}

extern "C" void kernel_launch(void* const* d_in, const int* in_sizes, int n_in,
                              void* d_out, int out_size, void* d_ws, size_t ws_size,
                              hipStream_t stream) {
    const float* x    = (const float*)d_in[0];
    const float* Wih1 = (const float*)d_in[1];
    const float* Whh1 = (const float*)d_in[2];
    const float* Wih2 = (const float*)d_in[3];
    const float* Whh2 = (const float*)d_in[4];
    const float* Wfc  = (const float*)d_in[5];
    const float* bfc  = (const float*)d_in[6];
    float* out = (float*)d_out;
    float* ws  = (float*)d_ws;

    prep<<<(212992 + 255) / 256, 256, 0, stream>>>(Whh1, Wih2, Whh2, Wfc, ws);
    lstm_l1<<<512, 1024, 0, stream>>>(x, Wih1, ws);
    lstm_l2<<<512, 1024, 0, stream>>>(bfc, ws, out);
}